// Round 11
// baseline (173.729 us; speedup 1.0000x reference)
//
#include <hip/hip_runtime.h>
#include <math.h>

constexpr int B_  = 2;
constexpr int N_  = 10000;
constexpr int E_  = 160000;
constexpr int H_  = 128;
constexpr int ET_ = 8;
constexpr int CAP_ = 64;               // slots per tgt node; P(deg>=64) ~ 2e-18
constexpr float EPS_ = 1e-5f;
constexpr float RSQH = 0.08838834764831845f; // 1/sqrt(128)

typedef __bf16 bf16x8 __attribute__((ext_vector_type(8)));
typedef short  short8 __attribute__((ext_vector_type(8)));
typedef float  f32x4  __attribute__((ext_vector_type(4)));
typedef unsigned short u16;

__device__ inline u16 bf16b(float f) {
    return __builtin_bit_cast(u16, (__bf16)f);
}

__device__ inline bf16x8 ldfrag(const u16* __restrict__ W, int kc, int nt, int lane) {
    short8 s = *(const short8*)(W + ((kc * 8 + nt) * 64 + lane) * 8);
    return __builtin_bit_cast(bf16x8, s);
}

// ---------------------------------------------------------------------------
// Setup: blocks [0,56) weight-prep, [56,64) edge-type tables,
// [64,74) zero count[].  (unchanged from R8)
// ---------------------------------------------------------------------------
__global__ __launch_bounds__(256)
void setup_kernel(const float* __restrict__ W1, const float* __restrict__ W2,
                  const float* __restrict__ Wq, const float* __restrict__ Wk,
                  const float* __restrict__ Wv,
                  u16* __restrict__ W1s, u16* __restrict__ W2s,
                  u16* __restrict__ Wqs, u16* __restrict__ Wks, u16* __restrict__ Wvs,
                  const float* __restrict__ edge_emb,
                  const float* __restrict__ bk, const float* __restrict__ bv,
                  const float* __restrict__ We, const float* __restrict__ be,
                  float* __restrict__ Kt, float* __restrict__ Vt, float* __restrict__ eb,
                  int* __restrict__ count)
{
    const int bid = blockIdx.x, tid = threadIdx.x;
    if (bid < 56) {
        int unit = bid >> 1, half = bid & 1;
        const float* src; u16* dst; int kc;
        if (unit < 12)      { src = W1; dst = W1s; kc = unit; }
        else if (unit < 16) { src = W2; dst = W2s; kc = unit - 12; }
        else if (unit < 20) { src = Wq; dst = Wqs; kc = unit - 16; }
        else if (unit < 24) { src = Wk; dst = Wks; kc = unit - 20; }
        else                { src = Wv; dst = Wvs; kc = unit - 24; }
        int nt = half * 4 + (tid >> 6), lane = tid & 63;
        int q = lane >> 4, c = lane & 15;
        int kbase = kc * 32 + q * 8;
        int col = nt * 16 + c;
        u16* out = dst + ((kc * 8 + nt) * 64 + lane) * 8;
#pragma unroll
        for (int j = 0; j < 8; ++j)
            out[j] = bf16b(src[(kbase + j) * H_ + col]);
    } else if (bid < 64) {
        int t = bid - 56;
        const float* ep = edge_emb + t * H_;
        __shared__ float red[2];
        int j = tid;
        if (j < 128) {
            float ak = bk[j], av = bv[j];
            for (int d = 0; d < H_; d += 4) {
                float e0 = ep[d], e1 = ep[d+1], e2 = ep[d+2], e3 = ep[d+3];
                ak += e0*Wk[(d+0)*H_+j] + e1*Wk[(d+1)*H_+j] + e2*Wk[(d+2)*H_+j] + e3*Wk[(d+3)*H_+j];
                av += e0*Wv[(d+0)*H_+j] + e1*Wv[(d+1)*H_+j] + e2*Wv[(d+2)*H_+j] + e3*Wv[(d+3)*H_+j];
            }
            Kt[t*H_ + j] = ak;
            Vt[t*H_ + j] = av;
            float pe = ep[j] * We[j];
#pragma unroll
            for (int off = 32; off; off >>= 1) pe += __shfl_xor(pe, off);
            if ((j & 63) == 0) red[j >> 6] = pe;
        }
        __syncthreads();
        if (j == 0) eb[t] = red[0] + red[1] + be[0];
    } else {
        int i0 = (bid - 64) * 1024;
        for (int i = i0 + tid; i < i0 + 1024; i += 256)
            if (i < N_) count[i] = 0;
    }
}

// ---------------------------------------------------------------------------
// Fused scatter (blocks [0,625)) + Q/KV MFMA (blocks [625,938)).
// KV bf16 interleaved per node: [node][0..127]=K, [128..255]=V (R8 layout).
// ---------------------------------------------------------------------------
__global__ __launch_bounds__(256)
void scatter_qkv_kernel(const int* __restrict__ src, const int* __restrict__ tgt,
                        const int* __restrict__ type, int* __restrict__ count,
                        int* __restrict__ slots,
                        const float* __restrict__ hidden, const float* __restrict__ time_emb,
                        const u16* __restrict__ Wqs, const u16* __restrict__ Wks,
                        const u16* __restrict__ Wvs, const float* __restrict__ bq,
                        u16* __restrict__ Q, u16* __restrict__ KV)
{
    if (blockIdx.x < 625) {
        int e = blockIdx.x * 256 + threadIdx.x;
        if (e < E_) {
            int t = tgt[e];
            int pos = atomicAdd(&count[t], 1);
            slots[t * CAP_ + pos] = src[e] | (type[e] << 16);
        }
        return;
    }
    const int wv = threadIdx.x >> 6, lane = threadIdx.x & 63;
    const int tile = (blockIdx.x - 625) * 4 + wv;
    if (tile >= (B_ * N_) / 16) return;
    const int nbase = tile * 16;
    const int m = lane & 15, q = lane >> 4;
    const int koff = q * 8;

    bf16x8 aq[4], av[4];
    const float* hp = hidden   + (nbase + m) * H_ + koff;
    const float* tp = time_emb + (nbase + m) * H_ + koff;
#pragma unroll
    for (int kc = 0; kc < 4; ++kc) {
        float4 h0 = *(const float4*)(hp + kc * 32);
        float4 h1 = *(const float4*)(hp + kc * 32 + 4);
        float4 t0 = *(const float4*)(tp + kc * 32);
        float4 t1 = *(const float4*)(tp + kc * 32 + 4);
        bf16x8 fv, fq;
        fv[0]=(__bf16)h0.x; fv[1]=(__bf16)h0.y; fv[2]=(__bf16)h0.z; fv[3]=(__bf16)h0.w;
        fv[4]=(__bf16)h1.x; fv[5]=(__bf16)h1.y; fv[6]=(__bf16)h1.z; fv[7]=(__bf16)h1.w;
        fq[0]=(__bf16)(h0.x+t0.x); fq[1]=(__bf16)(h0.y+t0.y);
        fq[2]=(__bf16)(h0.z+t0.z); fq[3]=(__bf16)(h0.w+t0.w);
        fq[4]=(__bf16)(h1.x+t1.x); fq[5]=(__bf16)(h1.y+t1.y);
        fq[6]=(__bf16)(h1.z+t1.z); fq[7]=(__bf16)(h1.w+t1.w);
        av[kc] = fv; aq[kc] = fq;
    }

    f32x4 accq[8], acck[8], accv[8];
#pragma unroll
    for (int nt = 0; nt < 8; ++nt) { accq[nt] = (f32x4)0.f; acck[nt] = (f32x4)0.f; accv[nt] = (f32x4)0.f; }

#pragma unroll
    for (int kc = 0; kc < 4; ++kc) {
#pragma unroll
        for (int nt = 0; nt < 8; ++nt) {
            bf16x8 bfq = ldfrag(Wqs, kc, nt, lane);
            bf16x8 bfk = ldfrag(Wks, kc, nt, lane);
            bf16x8 bfv = ldfrag(Wvs, kc, nt, lane);
            accq[nt] = __builtin_amdgcn_mfma_f32_16x16x32_bf16(aq[kc], bfq, accq[nt], 0, 0, 0);
            acck[nt] = __builtin_amdgcn_mfma_f32_16x16x32_bf16(aq[kc], bfk, acck[nt], 0, 0, 0);
            accv[nt] = __builtin_amdgcn_mfma_f32_16x16x32_bf16(av[kc], bfv, accv[nt], 0, 0, 0);
        }
    }

#pragma unroll
    for (int nt = 0; nt < 8; ++nt) {
        int col = nt * 16 + m;
        float bqc = bq[col];
#pragma unroll
        for (int r = 0; r < 4; ++r) {
            int node = nbase + q * 4 + r;
            Q[(size_t)node * H_ + col] = bf16b(accq[nt][r] + bqc);
            KV[(size_t)node * 256 + col]       = bf16b(acck[nt][r]);
            KV[(size_t)node * 256 + 128 + col] = bf16b(accv[nt][r]);
        }
    }
}

// ---------------------------------------------------------------------------
// Attention, BATCH-MERGED: one wave per NODE (2500 blocks x 4 waves = 10000
// waves) — edge_index is batch-independent, so both batches share slots,
// edge types, vt_s rows, and bias types.  Per 2-edge round a group issues
// 8 independent global loads (K,V x 2 edges x 2 batches) — double the
// loads-in-flight of R8 at the SAME serial round count — and one slot-shfl/
// vt read serves both batches.  Single-pass online softmax with deferred
// rescale (THR=8), independent (m,l,acc) per batch.
// ---------------------------------------------------------------------------
__global__ __launch_bounds__(256)
void attn_kernel(const u16* __restrict__ Qb, const u16* __restrict__ KV,
                 const float* __restrict__ Kt, const float* __restrict__ Vt,
                 const float* __restrict__ eb,
                 const int* __restrict__ count, const int* __restrict__ slots,
                 u16* __restrict__ aggb)
{
    __shared__ float bias_s[4][2][8];
    __shared__ __align__(16) u16 vt_s[8][128];

    const int tid = threadIdx.x;
    const int wv = tid >> 6, lane = tid & 63;
    const int g = lane >> 4, lam = lane & 15;

    for (int idx = tid; idx < ET_ * H_; idx += 256)
        vt_s[idx >> 7][idx & 127] = bf16b(Vt[idx]);
    __syncthreads();

    const int n = blockIdx.x * 4 + wv;
    const int cnt = count[n];
    const int sbase = n * CAP_;
    const u16* __restrict__ KV0 = KV;
    const u16* __restrict__ KV1 = KV + (size_t)N_ * 256;

    // preload slot list: lane lam of group g holds edge g + 4*lam
    int myslot = 0;
    {
        int idx = g + 4 * lam;
        if (idx < cnt) myslot = slots[sbase + idx];
    }
    const int lb = lane & 48;    // group base lane

    float q0[8], q1[8];
    {
        short8 sa = *(const short8*)(Qb + (size_t)n * H_ + lam * 8);
        short8 sb = *(const short8*)(Qb + (size_t)(N_ + n) * H_ + lam * 8);
        bf16x8 qa = __builtin_bit_cast(bf16x8, sa);
        bf16x8 qb = __builtin_bit_cast(bf16x8, sb);
#pragma unroll
        for (int j = 0; j < 8; ++j) { q0[j] = (float)qa[j]; q1[j] = (float)qb[j]; }
    }

    {   // per-type logit bias: group g computes types 2g, 2g+1 for BOTH batches
        const float* k0p = Kt + (2 * g) * H_ + lam * 8;
        const float* k1p = Kt + (2 * g + 1) * H_ + lam * 8;
        float p00 = 0.f, p01 = 0.f, p10 = 0.f, p11 = 0.f;
#pragma unroll
        for (int j = 0; j < 8; ++j) {
            float ka = k0p[j], kb = k1p[j];
            p00 += q0[j] * ka; p01 += q0[j] * kb;
            p10 += q1[j] * ka; p11 += q1[j] * kb;
        }
#pragma unroll
        for (int msk = 1; msk < 16; msk <<= 1) {
            p00 += __shfl_xor(p00, msk);
            p01 += __shfl_xor(p01, msk);
            p10 += __shfl_xor(p10, msk);
            p11 += __shfl_xor(p11, msk);
        }
        if (lam == 0) {
            bias_s[wv][0][2 * g]     = p00 * RSQH + eb[2 * g];
            bias_s[wv][0][2 * g + 1] = p01 * RSQH + eb[2 * g + 1];
            bias_s[wv][1][2 * g]     = p10 * RSQH + eb[2 * g];
            bias_s[wv][1][2 * g + 1] = p11 * RSQH + eb[2 * g + 1];
        }
    }
    // bias_s rows written and read by the same wave -> wave-synchronous

    float m0 = -INFINITY, l0 = 0.f, m1 = -INFINITY, l1 = 0.f;
    float acc0[8], acc1[8];
#pragma unroll
    for (int j = 0; j < 8; ++j) { acc0[j] = 0.f; acc1[j] = 0.f; }

    int c = g;
    for (; c + 4 < cnt; c += 8) {
        int r = (c - g) >> 2;                 // 0,2,4,...
        int pkA = __shfl(myslot, lb + r);
        int pkB = __shfl(myslot, lb + r + 1);
        int sA = pkA & 0xFFFF, tA = pkA >> 16;
        int sB = pkB & 0xFFFF, tB = pkB >> 16;
        // 8 loads in flight: K,V for both edges, both batches
        short8 k0A = *(const short8*)(KV0 + (size_t)sA * 256 + lam * 8);
        short8 k0B = *(const short8*)(KV0 + (size_t)sB * 256 + lam * 8);
        short8 k1A = *(const short8*)(KV1 + (size_t)sA * 256 + lam * 8);
        short8 k1B = *(const short8*)(KV1 + (size_t)sB * 256 + lam * 8);
        short8 v0A = *(const short8*)(KV0 + (size_t)sA * 256 + 128 + lam * 8);
        short8 v0B = *(const short8*)(KV0 + (size_t)sB * 256 + 128 + lam * 8);
        short8 v1A = *(const short8*)(KV1 + (size_t)sA * 256 + 128 + lam * 8);
        short8 v1B = *(const short8*)(KV1 + (size_t)sB * 256 + 128 + lam * 8);
        short8 vtA = *(const short8*)(&vt_s[tA][lam * 8]);
        short8 vtB = *(const short8*)(&vt_s[tB][lam * 8]);
        bf16x8 ka0A = __builtin_bit_cast(bf16x8, k0A);
        bf16x8 ka0B = __builtin_bit_cast(bf16x8, k0B);
        bf16x8 ka1A = __builtin_bit_cast(bf16x8, k1A);
        bf16x8 ka1B = __builtin_bit_cast(bf16x8, k1B);
        float d0A = 0.f, d0B = 0.f, d1A = 0.f, d1B = 0.f;
#pragma unroll
        for (int j = 0; j < 8; ++j) {
            d0A += q0[j] * (float)ka0A[j];
            d0B += q0[j] * (float)ka0B[j];
            d1A += q1[j] * (float)ka1A[j];
            d1B += q1[j] * (float)ka1B[j];
        }
#pragma unroll
        for (int msk = 1; msk < 16; msk <<= 1) {
            d0A += __shfl_xor(d0A, msk);
            d0B += __shfl_xor(d0B, msk);
            d1A += __shfl_xor(d1A, msk);
            d1B += __shfl_xor(d1B, msk);
        }
        float lg0A = d0A * RSQH + bias_s[wv][0][tA];
        float lg0B = d0B * RSQH + bias_s[wv][0][tB];
        float lg1A = d1A * RSQH + bias_s[wv][1][tA];
        float lg1B = d1B * RSQH + bias_s[wv][1][tB];
        bf16x8 va0A = __builtin_bit_cast(bf16x8, v0A);
        bf16x8 va0B = __builtin_bit_cast(bf16x8, v0B);
        bf16x8 va1A = __builtin_bit_cast(bf16x8, v1A);
        bf16x8 va1B = __builtin_bit_cast(bf16x8, v1B);
        bf16x8 vtaA = __builtin_bit_cast(bf16x8, vtA);
        bf16x8 vtaB = __builtin_bit_cast(bf16x8, vtB);
        // batch 0
        {
            float mx = fmaxf(lg0A, lg0B);
            if (mx > m0 + 8.f) {               // deferred rescale (T13)
                float rs = __expf(m0 - mx);    // first trigger: exp(-inf)=0
                l0 *= rs;
#pragma unroll
                for (int j = 0; j < 8; ++j) acc0[j] *= rs;
                m0 = mx;
            }
            float wA = __expf(lg0A - m0);
            float wB = __expf(lg0B - m0);
            l0 += wA + wB;
#pragma unroll
            for (int j = 0; j < 8; ++j)
                acc0[j] += wA * ((float)va0A[j] + (float)vtaA[j])
                         + wB * ((float)va0B[j] + (float)vtaB[j]);
        }
        // batch 1
        {
            float mx = fmaxf(lg1A, lg1B);
            if (mx > m1 + 8.f) {
                float rs = __expf(m1 - mx);
                l1 *= rs;
#pragma unroll
                for (int j = 0; j < 8; ++j) acc1[j] *= rs;
                m1 = mx;
            }
            float wA = __expf(lg1A - m1);
            float wB = __expf(lg1B - m1);
            l1 += wA + wB;
#pragma unroll
            for (int j = 0; j < 8; ++j)
                acc1[j] += wA * ((float)va1A[j] + (float)vtaA[j])
                         + wB * ((float)va1B[j] + (float)vtaB[j]);
        }
    }
    if (c < cnt) {
        int r = (c - g) >> 2;
        int pkA = __shfl(myslot, lb + r);
        int sA = pkA & 0xFFFF, tA = pkA >> 16;
        short8 k0A = *(const short8*)(KV0 + (size_t)sA * 256 + lam * 8);
        short8 k1A = *(const short8*)(KV1 + (size_t)sA * 256 + lam * 8);
        short8 v0A = *(const short8*)(KV0 + (size_t)sA * 256 + 128 + lam * 8);
        short8 v1A = *(const short8*)(KV1 + (size_t)sA * 256 + 128 + lam * 8);
        short8 vtA = *(const short8*)(&vt_s[tA][lam * 8]);
        bf16x8 ka0A = __builtin_bit_cast(bf16x8, k0A);
        bf16x8 ka1A = __builtin_bit_cast(bf16x8, k1A);
        float d0A = 0.f, d1A = 0.f;
#pragma unroll
        for (int j = 0; j < 8; ++j) {
            d0A += q0[j] * (float)ka0A[j];
            d1A += q1[j] * (float)ka1A[j];
        }
#pragma unroll
        for (int msk = 1; msk < 16; msk <<= 1) {
            d0A += __shfl_xor(d0A, msk);
            d1A += __shfl_xor(d1A, msk);
        }
        float lg0A = d0A * RSQH + bias_s[wv][0][tA];
        float lg1A = d1A * RSQH + bias_s[wv][1][tA];
        bf16x8 va0A = __builtin_bit_cast(bf16x8, v0A);
        bf16x8 va1A = __builtin_bit_cast(bf16x8, v1A);
        bf16x8 vtaA = __builtin_bit_cast(bf16x8, vtA);
        if (lg0A > m0 + 8.f) {
            float rs = __expf(m0 - lg0A);
            l0 *= rs;
#pragma unroll
            for (int j = 0; j < 8; ++j) acc0[j] *= rs;
            m0 = lg0A;
        }
        float w0 = __expf(lg0A - m0);
        l0 += w0;
#pragma unroll
        for (int j = 0; j < 8; ++j)
            acc0[j] += w0 * ((float)va0A[j] + (float)vtaA[j]);
        if (lg1A > m1 + 8.f) {
            float rs = __expf(m1 - lg1A);
            l1 *= rs;
#pragma unroll
            for (int j = 0; j < 8; ++j) acc1[j] *= rs;
            m1 = lg1A;
        }
        float w1 = __expf(lg1A - m1);
        l1 += w1;
#pragma unroll
        for (int j = 0; j < 8; ++j)
            acc1[j] += w1 * ((float)va1A[j] + (float)vtaA[j]);
    }

    // merge the 4 groups per batch (reconverged): max + rescale + sum
    {
        float M = fmaxf(m0, __shfl_xor(m0, 16));
        M = fmaxf(M, __shfl_xor(M, 32));
        float rs = (m0 == M) ? 1.f : __expf(m0 - M);  // guards -inf - -inf = NaN
        l0 *= rs;
#pragma unroll
        for (int j = 0; j < 8; ++j) {
            acc0[j] *= rs;
            acc0[j] += __shfl_xor(acc0[j], 16);
            acc0[j] += __shfl_xor(acc0[j], 32);
        }
        l0 += __shfl_xor(l0, 16);
        l0 += __shfl_xor(l0, 32);
    }
    {
        float M = fmaxf(m1, __shfl_xor(m1, 16));
        M = fmaxf(M, __shfl_xor(M, 32));
        float rs = (m1 == M) ? 1.f : __expf(m1 - M);
        l1 *= rs;
#pragma unroll
        for (int j = 0; j < 8; ++j) {
            acc1[j] *= rs;
            acc1[j] += __shfl_xor(acc1[j], 16);
            acc1[j] += __shfl_xor(acc1[j], 32);
        }
        l1 += __shfl_xor(l1, 16);
        l1 += __shfl_xor(l1, 32);
    }

    if (g == 0) {
        float invL0 = (cnt > 0) ? 1.f / l0 : 0.f;
        float invL1 = (cnt > 0) ? 1.f / l1 : 0.f;
        bf16x8 o0, o1;
#pragma unroll
        for (int j = 0; j < 8; ++j) {
            o0[j] = (__bf16)(acc0[j] * invL0);
            o1[j] = (__bf16)(acc1[j] * invL1);
        }
        *(short8*)(aggb + (size_t)n * H_ + lam * 8)        = __builtin_bit_cast(short8, o0);
        *(short8*)(aggb + (size_t)(N_ + n) * H_ + lam * 8) = __builtin_bit_cast(short8, o1);
    }
}

// ---------------------------------------------------------------------------
// MLP + residual + LayerNorm via MFMA.  313 blocks x 4 waves.  Unchanged.
// ---------------------------------------------------------------------------
__global__ __launch_bounds__(256)
void mlp_mfma_kernel(const float* __restrict__ hidden, const u16* __restrict__ aggb,
                     const float* __restrict__ time_emb,
                     const u16* __restrict__ W1s, const u16* __restrict__ W2s,
                     const float* __restrict__ b1, const float* __restrict__ b2,
                     const float* __restrict__ gamma, const float* __restrict__ beta,
                     float* __restrict__ out)
{
    __shared__ __align__(16) u16 h1s[4][16][136];
    const int wv = threadIdx.x >> 6, lane = threadIdx.x & 63;
    const int tile = blockIdx.x * 4 + wv;
    if (tile >= (B_ * N_) / 16) return;
    const int nbase = tile * 16;
    const int m = lane & 15, q = lane >> 4;
    const int koff = q * 8;

    bf16x8 a[12];
    const float* hp = hidden   + (nbase + m) * H_ + koff;
    const float* tp = time_emb + (nbase + m) * H_ + koff;
    const u16*   ap = aggb + (size_t)(nbase + m) * H_ + koff;
#pragma unroll
    for (int kc = 0; kc < 4; ++kc) {
        float4 h0 = *(const float4*)(hp + kc * 32);
        float4 h1 = *(const float4*)(hp + kc * 32 + 4);
        float4 t0 = *(const float4*)(tp + kc * 32);
        float4 t1 = *(const float4*)(tp + kc * 32 + 4);
        bf16x8 fh, ft;
        fh[0]=(__bf16)h0.x; fh[1]=(__bf16)h0.y; fh[2]=(__bf16)h0.z; fh[3]=(__bf16)h0.w;
        fh[4]=(__bf16)h1.x; fh[5]=(__bf16)h1.y; fh[6]=(__bf16)h1.z; fh[7]=(__bf16)h1.w;
        ft[0]=(__bf16)t0.x; ft[1]=(__bf16)t0.y; ft[2]=(__bf16)t0.z; ft[3]=(__bf16)t0.w;
        ft[4]=(__bf16)t1.x; ft[5]=(__bf16)t1.y; ft[6]=(__bf16)t1.z; ft[7]=(__bf16)t1.w;
        a[0 * 4 + kc] = fh;
        a[2 * 4 + kc] = ft;
        short8 s8 = *(const short8*)(ap + kc * 32);
        a[1 * 4 + kc] = __builtin_bit_cast(bf16x8, s8);
    }

    f32x4 acc[8];
#pragma unroll
    for (int nt = 0; nt < 8; ++nt) acc[nt] = (f32x4)0.f;
#pragma unroll
    for (int kc = 0; kc < 12; ++kc) {
#pragma unroll
        for (int nt = 0; nt < 8; ++nt) {
            bf16x8 bf = ldfrag(W1s, kc, nt, lane);
            acc[nt] = __builtin_amdgcn_mfma_f32_16x16x32_bf16(a[kc], bf, acc[nt], 0, 0, 0);
        }
    }

#pragma unroll
    for (int nt = 0; nt < 8; ++nt) {
        int col = nt * 16 + m;
        float bb = b1[col];
#pragma unroll
        for (int r = 0; r < 4; ++r) {
            float v = acc[nt][r] + bb;
            float h = v / (1.f + __expf(-v));
            h1s[wv][q * 4 + r][col] = bf16b(h);
        }
    }

    f32x4 acc2[8];
#pragma unroll
    for (int nt = 0; nt < 8; ++nt) acc2[nt] = (f32x4)0.f;
#pragma unroll
    for (int kc = 0; kc < 4; ++kc) {
        short8 s8 = *(const short8*)&h1s[wv][m][kc * 32 + koff];
        bf16x8 a2 = __builtin_bit_cast(bf16x8, s8);
#pragma unroll
        for (int nt = 0; nt < 8; ++nt) {
            bf16x8 bf = ldfrag(W2s, kc, nt, lane);
            acc2[nt] = __builtin_amdgcn_mfma_f32_16x16x32_bf16(a2, bf, acc2[nt], 0, 0, 0);
        }
    }

    float x[8][4];
#pragma unroll
    for (int nt = 0; nt < 8; ++nt) {
        int col = nt * 16 + m;
        float bb = b2[col];
#pragma unroll
        for (int r = 0; r < 4; ++r) {
            int node = nbase + q * 4 + r;
            x[nt][r] = hidden[node * H_ + col] + acc2[nt][r] + bb;
        }
    }
#pragma unroll
    for (int r = 0; r < 4; ++r) {
        float s = 0.f, ss = 0.f;
#pragma unroll
        for (int nt = 0; nt < 8; ++nt) { s += x[nt][r]; ss += x[nt][r] * x[nt][r]; }
#pragma unroll
        for (int off = 1; off < 16; off <<= 1) {
            s  += __shfl_xor(s, off);
            ss += __shfl_xor(ss, off);
        }
        float mu  = s * (1.f / H_);
        float var = ss * (1.f / H_) - mu * mu;
        float rs  = rsqrtf(var + EPS_);
        int node = nbase + q * 4 + r;
#pragma unroll
        for (int nt = 0; nt < 8; ++nt) {
            int col = nt * 16 + m;
            out[node * H_ + col] = (x[nt][r] - mu) * rs * gamma[col] + beta[col];
        }
    }
}

// ---------------------------------------------------------------------------
extern "C" void kernel_launch(void* const* d_in, const int* in_sizes, int n_in,
                              void* d_out, int out_size, void* d_ws, size_t ws_size,
                              hipStream_t stream)
{
    const float* hidden   = (const float*)d_in[0];
    const float* time_emb = (const float*)d_in[1];
    const int*   eidx     = (const int*)d_in[2];
    const int*   etype    = (const int*)d_in[3];
    const float* edge_emb = (const float*)d_in[4];
    const float* Wq = (const float*)d_in[5];
    const float* bq = (const float*)d_in[6];
    const float* Wk = (const float*)d_in[7];
    const float* bk = (const float*)d_in[8];
    const float* Wv = (const float*)d_in[9];
    const float* bv = (const float*)d_in[10];
    const float* We = (const float*)d_in[11];
    const float* be = (const float*)d_in[12];
    const float* W1 = (const float*)d_in[13];
    const float* b1 = (const float*)d_in[14];
    const float* W2 = (const float*)d_in[15];
    const float* b2 = (const float*)d_in[16];
    const float* gamma = (const float*)d_in[17];
    const float* beta  = (const float*)d_in[18];
    float* out = (float*)d_out;

    constexpr int BNH = B_ * N_ * H_;
    u16* Qb   = (u16*)d_ws;                 // B*N*128 bf16
    u16* KVb  = Qb + BNH;                   // B*N*256 bf16 (K|V interleaved)
    u16* aggb = KVb + (size_t)B_ * N_ * 256;
    float* Kt  = (float*)(aggb + BNH);
    float* Vt  = Kt + ET_ * H_;
    float* ebt = Vt + ET_ * H_;
    int* count = (int*)(ebt + ET_);
    int* slots = count + N_;                // N*CAP ints
    uintptr_t wp = (uintptr_t)(slots + N_ * CAP_);
    wp = (wp + 15) & ~(uintptr_t)15;
    u16* W1s = (u16*)wp;
    u16* W2s = W1s + 384 * 128;
    u16* Wqs = W2s + 128 * 128;
    u16* Wks = Wqs + 128 * 128;
    u16* Wvs = Wks + 128 * 128;

    const int* esrc = eidx;
    const int* etgt = eidx + E_;

    setup_kernel<<<74, 256, 0, stream>>>(
        W1, W2, Wq, Wk, Wv, W1s, W2s, Wqs, Wks, Wvs,
        edge_emb, bk, bv, We, be, Kt, Vt, ebt, count);
    scatter_qkv_kernel<<<625 + 313, 256, 0, stream>>>(
        esrc, etgt, etype, count, slots,
        hidden, time_emb, Wqs, Wks, Wvs, bq, Qb, KVb);
    attn_kernel<<<N_ / 4, 256, 0, stream>>>(
        Qb, KVb, Kt, Vt, ebt, count, slots, aggb);
    mlp_mfma_kernel<<<313, 256, 0, stream>>>(
        hidden, aggb, time_emb, W1s, W2s, b1, b2, gamma, beta, out);
}